// Round 5
// baseline (310.725 us; speedup 1.0000x reference)
//
#include <hip/hip_runtime.h>
#include <math.h>

// Problem constants (fixed by setup_inputs)
#define N_NODES 1024
#define F_DIM   1024
#define H_DIM   512
#define E_EDGES 32768
#define B_GRAPHS 16
#define OUT_DIM 10
#define FH_DIM  1536
#define EPS 1e-5f
#define MH_C_D 0.8673250705840776
#define C2_D   0.72134752044448170368   // 0.5*log2(e)
#define C2_F   ((float)C2_D)
#define CSC    0.84932180028801904272f  // sqrt(C2)
#define WC2F   ((float)(MH_C_D / C2_D)) // MH_C / C2
#define MH_C_F ((float)MH_C_D)
#define INV_SQRT2 0.70710678118654752440f

typedef float v2f __attribute__((ext_vector_type(2)));
typedef unsigned int u32;
typedef const __attribute__((address_space(1))) u32 gu32;
typedef __attribute__((address_space(3))) u32 lu32;

#if __has_builtin(__builtin_amdgcn_exp2f)
#define EXP2NEG(x) __builtin_amdgcn_exp2f(-(x))   // exp2(-x), neg is free src modifier
#else
#define EXP2NEG(x) __expf(-0.69314718055994530942f * (x))
#endif

// ---- packed fp32 asm helpers (dual-rate FP32; op_sel broadcasts; HW-verified R3/R4) ----
// d = a * bcast(p.lo) + bcast(p.hi)
#define PK_FMA_BB(d, a, p) \
    asm("v_pk_fma_f32 %0, %1, %2, %2 op_sel:[0,0,1] op_sel_hi:[1,0,1]" \
        : "=v"(d) : "v"(a), "v"(p))
// d = a * b (plain packed)
#define PK_MUL2(d, a, b) \
    asm("v_pk_mul_f32 %0, %1, %2" : "=v"(d) : "v"(a), "v"(b))

// ---------------- KA: fused setup = h (2048) + pk (1024) + zero4096 (16) + zero vb (2048)
__global__ __launch_bounds__(256) void k_setup(const float* __restrict__ x,
                                               const float* __restrict__ watt,
                                               float* __restrict__ h,
                                               const float* __restrict__ scale,
                                               const float* __restrict__ trans,
                                               const float* __restrict__ ww,
                                               float* __restrict__ pk,
                                               float* __restrict__ zbase,
                                               float* __restrict__ vb) {
    const int bid = blockIdx.x;
    const int t = threadIdx.x;
    if (bid < 2048) {
        // Haar split + attention gate -> h
        int idx = bid * 256 + t;                      // 0 .. N*H-1
        float2 p = ((const float2*)x)[idx];
        float lo = (p.x + p.y) * INV_SQRT2;
        float hi = (p.x - p.y) * INV_SQRT2;
        float tt = lo * watt[0] + hi * watt[1];
        float sc = 1.0f / (1.0f + __expf(-tt));
        h[idx] = sc * lo + (1.0f - sc) * hi;
    } else if (bid < 3072) {
        // pack params pk[o][i] = (C/scale, -C*trans/scale, wz=-MH*ww/C2, wc=MH*ww)
        int g = (bid - 2048) * 256 + t;               // 0 .. 512*512-1
        float iv = 1.0f / scale[g];
        float wwv = ww[g];
        float4 p;
        p.x = iv * CSC;
        p.y = -(trans[g] * iv * CSC);
        p.z = -(wwv * WC2F);
        p.w = wwv * MH_C_F;
        ((float4*)pk)[g] = p;
    } else if (bid < 3088) {
        // zero colsum/colsum2/xsum/xsum2 (3072) + deg (1024) — contiguous 4096 floats
        zbase[(bid - 3072) * 256 + t] = 0.0f;
    } else {
        // zero vb (524288 floats) — wavelet/base accumulate atomically into it
        vb[(bid - 3088) * 256 + t] = 0.0f;
    }
}

// ---------------- KB: fused k_hist (128 wg) + k_xstats (64 wg) ----------------
__global__ __launch_bounds__(256) void k_hx(const int* __restrict__ dst,
                                            int* __restrict__ deg,
                                            const float* __restrict__ x,
                                            float* __restrict__ xsum,
                                            float* __restrict__ xsum2) {
    const int bid = blockIdx.x;
    const int t = threadIdx.x;
    if (bid < 128) {
        int e = bid * 256 + t;
        atomicAdd(&deg[dst[e]], 1);
    } else {
        const int n0 = (bid - 128) * 16;              // 64 blocks x 16 rows
        float s[4] = {}, s2[4] = {};
        for (int r = 0; r < 16; ++r) {
            #pragma unroll
            for (int ch = 0; ch < 4; ++ch) {
                float v = x[(n0 + r) * F_DIM + ch * 256 + t];
                s[ch] += v; s2[ch] += v * v;
            }
        }
        #pragma unroll
        for (int ch = 0; ch < 4; ++ch) {
            unsafeAtomicAdd(&xsum[ch * 256 + t], s[ch]);
            unsafeAtomicAdd(&xsum2[ch * 256 + t], s2[ch]);
        }
    }
}

// shfl-based scan: per-wave inclusive scan + cross-wave fixup
__global__ __launch_bounds__(1024) void k_scan(const int* __restrict__ deg,
                                               int* __restrict__ start,
                                               int* __restrict__ cursor) {
    __shared__ int wsum[16];
    int t = threadIdx.x;
    int lane = t & 63, wid = t >> 6;
    int v = deg[t];
    int x = v;
    #pragma unroll
    for (int off = 1; off < 64; off <<= 1) {
        int y = __shfl_up(x, off, 64);
        if (lane >= off) x += y;
    }
    if (lane == 63) wsum[wid] = x;
    __syncthreads();
    if (t < 16) {
        int w = wsum[t];
        int xs = w;
        #pragma unroll
        for (int off = 1; off < 16; off <<= 1) {
            int y = __shfl_up(xs, off, 64);
            if (t >= off) xs += y;
        }
        wsum[t] = xs - w;   // exclusive prefix of wave sums
    }
    __syncthreads();
    int excl = wsum[wid] + x - v;
    start[t] = excl;
    cursor[t] = excl;
}

__global__ __launch_bounds__(256) void k_fill(const int* __restrict__ src,
                                              const int* __restrict__ dst,
                                              int* __restrict__ cursor,
                                              int* __restrict__ elist) {
    int e = blockIdx.x * 256 + threadIdx.x;
    int slot = atomicAdd(&cursor[dst[e]], 1);
    elist[slot] = src[e];
}

// ---------------- K2: gather (atomic-free scatter-add), float2 + unroll4 ----------------
__global__ __launch_bounds__(256) void k_gather(const float* __restrict__ h,
                                                const int* __restrict__ start,
                                                const int* __restrict__ deg,
                                                const int* __restrict__ elist,
                                                float* __restrict__ agg) {
    int d = blockIdx.x;
    int t = threadIdx.x;
    int st = start[d], dg = deg[d];
    const float2* h2 = (const float2*)h;
    float2 a = h2[d * 256 + t];
    int k = 0;
    for (; k + 4 <= dg; k += 4) {
        int s0 = elist[st + k];
        int s1 = elist[st + k + 1];
        int s2 = elist[st + k + 2];
        int s3 = elist[st + k + 3];
        float2 v0 = h2[s0 * 256 + t];
        float2 v1 = h2[s1 * 256 + t];
        float2 v2 = h2[s2 * 256 + t];
        float2 v3 = h2[s3 * 256 + t];
        a.x += (v0.x + v1.x) + (v2.x + v3.x);
        a.y += (v0.y + v1.y) + (v2.y + v3.y);
    }
    for (; k < dg; ++k) {
        int s0 = elist[st + k];
        float2 v0 = h2[s0 * 256 + t];
        a.x += v0.x; a.y += v0.y;
    }
    ((float2*)agg)[d * 256 + t] = a;
}

// ---------------- K2b: transpose agg [n][i] -> aggT [i][n] ----------------
__global__ __launch_bounds__(256) void k_transpose(const float* __restrict__ agg,
                                                   float* __restrict__ aggT) {
    __shared__ float tile[64 * 65];
    const int t = threadIdx.x;
    const int n0 = blockIdx.x * 64;
    const int i0 = blockIdx.y * 64;
    #pragma unroll
    for (int v = 0; v < 4; ++v) {
        int flat = v * 256 + t;
        int r = flat >> 4, c4 = flat & 15;
        float4 a = *(const float4*)&agg[(n0 + r) * H_DIM + i0 + c4 * 4];
        tile[(c4 * 4 + 0) * 65 + r] = a.x;
        tile[(c4 * 4 + 1) * 65 + r] = a.y;
        tile[(c4 * 4 + 2) * 65 + r] = a.z;
        tile[(c4 * 4 + 3) * 65 + r] = a.w;
    }
    __syncthreads();
    #pragma unroll
    for (int v = 0; v < 4; ++v) {
        int flat = v * 256 + t;
        int il = flat >> 4, c4 = flat & 15;
        float4 a;
        a.x = tile[il * 65 + c4 * 4 + 0];
        a.y = tile[il * 65 + c4 * 4 + 1];
        a.z = tile[il * 65 + c4 * 4 + 2];
        a.w = tile[il * 65 + c4 * 4 + 3];
        *(float4*)&aggT[(i0 + il) * N_NODES + n0 + c4 * 4] = a;
    }
}

// ---------------- K3: wavelet only (base split out); 8n x 2o per thread ----------------
// LDS: 0.25 ds_read_b128 per element (halved); sP[ii][o] unpadded float4 layout is
// conflict-free for this access pattern: reads vary og (stride 8 banks, 2-way+bcast),
// writes vary o=t>>4 (4 distinct bank-groups, 16-lane bcast). 40KB = 4 blocks/CU.
#define TN 64
#define TO 64
#define KI 16
#define ZSPLIT 8
#define ZLEN (H_DIM / ZSPLIT)   // 64
#define NSTG (ZLEN / KI)        // 4
__global__ __launch_bounds__(256) void k_wavelet(const float* __restrict__ aggT,
                                                 const float* __restrict__ pk,
                                                 float* __restrict__ vb) {
    __shared__ float  sA[2][KI * TN];    // 4KB x2   [i][n]
    __shared__ float4 sP[2][KI * TO];    // 16KB x2  [i][o]

    const int t  = threadIdx.x;
    const int n0 = blockIdx.x * TN;
    const int o0 = blockIdx.y * TO;
    const int z0 = blockIdx.z * ZLEN;
    const int nb8 = (t & 7) * 8;         // 8 n per thread
    const int og  = t >> 3;              // 32 groups
    const int ob2 = og * 2;              // 2 o per thread

    // staging decomposition
    const int srow = t >> 4, scol4 = (t & 15) * 4;   // A: row i, 4 cols n
    const int pio = t >> 4, pic = t & 15;            // P: thread covers o = j*16+pio, ii=pic
    const float4* pk4 = (const float4*)pk;

    v2f accw[2][4] = {};   // [oo][npair]

    // prologue: stage 0
    {
        int g = (z0 + srow) * N_NODES + n0 + scol4;
        __builtin_amdgcn_global_load_lds((gu32*)&aggT[g], (lu32*)&sA[0][t * 4], 16, 0, 0);
        float4 pr[4];
        #pragma unroll
        for (int j = 0; j < 4; ++j)
            pr[j] = pk4[(size_t)(o0 + j * 16 + pio) * H_DIM + z0 + pic];
        #pragma unroll
        for (int j = 0; j < 4; ++j)
            sP[0][pic * TO + j * 16 + pio] = pr[j];
    }
    __syncthreads();

    for (int stg = 0; stg < NSTG; ++stg) {
        const int i0 = z0 + stg * KI;
        const int nb = (stg + 1) & 1;
        float4 pr[4];
        if (stg + 1 < NSTG) {
            int g = (i0 + KI + srow) * N_NODES + n0 + scol4;
            __builtin_amdgcn_global_load_lds((gu32*)&aggT[g], (lu32*)&sA[nb][t * 4], 16, 0, 0);
            #pragma unroll
            for (int j = 0; j < 4; ++j)
                pr[j] = pk4[(size_t)(o0 + j * 16 + pio) * H_DIM + i0 + KI + pic];
        }
        const float*  pA = sA[stg & 1];
        const float4* pP = sP[stg & 1];
        #pragma unroll
        for (int ii = 0; ii < KI; ++ii) {
            const float4 af0 = *(const float4*)&pA[ii * TN + nb8];
            const float4 af1 = *(const float4*)&pA[ii * TN + nb8 + 4];
            v2f a01 = {af0.x, af0.y}, a23 = {af0.z, af0.w};
            v2f a45 = {af1.x, af1.y}, a67 = {af1.z, af1.w};
            #pragma unroll
            for (int oo = 0; oo < 2; ++oo) {
                float4 pq = pP[ii * TO + ob2 + oo];
                v2f pxy = {pq.x, pq.y};    // {ivC, -tfC}
                v2f pzw = {pq.z, pq.w};    // {wz, wc}
                v2f y0, y1, y2, y3, q0, q1, q2, q3, w0, w1, w2, w3;
                PK_FMA_BB(y0, a01, pxy); PK_FMA_BB(y1, a23, pxy);
                PK_FMA_BB(y2, a45, pxy); PK_FMA_BB(y3, a67, pxy);
                PK_MUL2(q0, y0, y0); PK_MUL2(q1, y1, y1);
                PK_MUL2(q2, y2, y2); PK_MUL2(q3, y3, y3);
                PK_FMA_BB(w0, q0, pzw); PK_FMA_BB(w1, q1, pzw);
                PK_FMA_BB(w2, q2, pzw); PK_FMA_BB(w3, q3, pzw);
                accw[oo][0].x += w0.x * EXP2NEG(q0.x);
                accw[oo][0].y += w0.y * EXP2NEG(q0.y);
                accw[oo][1].x += w1.x * EXP2NEG(q1.x);
                accw[oo][1].y += w1.y * EXP2NEG(q1.y);
                accw[oo][2].x += w2.x * EXP2NEG(q2.x);
                accw[oo][2].y += w2.y * EXP2NEG(q2.y);
                accw[oo][3].x += w3.x * EXP2NEG(q3.x);
                accw[oo][3].y += w3.y * EXP2NEG(q3.y);
            }
        }
        if (stg + 1 < NSTG) {
            #pragma unroll
            for (int j = 0; j < 4; ++j)
                sP[nb][pic * TO + j * 16 + pio] = pr[j];
        }
        __syncthreads();
    }
    // atomic accumulate into vb (ZSPLIT contributions per (n,o) + base)
    const int oc = o0 + ob2;
    #pragma unroll
    for (int p = 0; p < 4; ++p) {
        int ne = n0 + nb8 + 2 * p;
        unsafeAtomicAdd(&vb[(size_t)ne * H_DIM + oc],           accw[0][p].x);
        unsafeAtomicAdd(&vb[(size_t)ne * H_DIM + oc + 1],       accw[1][p].x);
        unsafeAtomicAdd(&vb[(size_t)(ne + 1) * H_DIM + oc],     accw[0][p].y);
        unsafeAtomicAdd(&vb[(size_t)(ne + 1) * H_DIM + oc + 1], accw[1][p].y);
    }
}

// ---------------- K3b: base GEMM  vb += silu(agg) @ bw^T  (fp32, 32x32 tiles) ---------
__global__ __launch_bounds__(256) void k_base(const float* __restrict__ aggT,
                                              const float* __restrict__ bw,
                                              float* __restrict__ vb) {
    __shared__ float sA[16][32];
    __shared__ float sB[16][33];
    const int t = threadIdx.x;
    const int n0 = blockIdx.x * 32, o0 = blockIdx.y * 32;
    const int nl = (t & 15) * 2, ol = (t >> 4) * 2;
    float acc[2][2] = {};
    for (int ic = 0; ic < 32; ++ic) {
        int i0 = ic * 16;
        __syncthreads();
        {
            int flat = t * 2;
            int r = flat >> 5, c = flat & 31;
            float2 av = *(const float2*)&aggT[(i0 + r) * N_NODES + n0 + c];
            sA[r][c]     = av.x / (1.0f + __expf(-av.x));   // silu on the fly
            sA[r][c + 1] = av.y / (1.0f + __expf(-av.y));
            int ob = t >> 3, iq = (t & 7) * 2;
            float2 bv = *(const float2*)&bw[(o0 + ob) * H_DIM + i0 + iq];
            sB[iq][ob]     = bv.x;
            sB[iq + 1][ob] = bv.y;
        }
        __syncthreads();
        #pragma unroll
        for (int ii = 0; ii < 16; ++ii) {
            float a0 = sA[ii][nl], a1 = sA[ii][nl + 1];
            float b0 = sB[ii][ol], b1 = sB[ii][ol + 1];
            acc[0][0] += a0 * b0; acc[0][1] += a0 * b1;
            acc[1][0] += a1 * b0; acc[1][1] += a1 * b1;
        }
    }
    #pragma unroll
    for (int j = 0; j < 2; ++j)
        #pragma unroll
        for (int k = 0; k < 2; ++k)
            unsafeAtomicAdd(&vb[(size_t)(n0 + nl + j) * H_DIM + o0 + ol + k], acc[j][k]);
}

// ---------------- K4: column stats of final vb (16 blocks x 32 cols) ----------------
__global__ __launch_bounds__(256) void k_stats(const float* __restrict__ vb,
                                               float* __restrict__ colsum,
                                               float* __restrict__ colsum2) {
    const int t = threadIdx.x;
    const int c = blockIdx.x * 32 + (t & 31);
    const int p = t >> 5;                 // 8 n-parts x 128 rows
    float s = 0.f, s2 = 0.f;
    for (int r = 0; r < 128; ++r) {
        float v = vb[(size_t)(p * 128 + r) * H_DIM + c];
        s += v; s2 += v * v;
    }
    __shared__ float sh1[256], sh2[256];
    sh1[t] = s; sh2[t] = s2;
    __syncthreads();
    if (t < 32) {
        float a = 0.f, a2 = 0.f;
        #pragma unroll
        for (int q = 0; q < 8; ++q) { a += sh1[q * 32 + t]; a2 += sh2[q * 32 + t]; }
        colsum[blockIdx.x * 32 + t]  = a;
        colsum2[blockIdx.x * 32 + t] = a2;
    }
}

// ---------------- K7: pool + inline BN-param + inline graph-range ----------------
__global__ __launch_bounds__(256) void k_pool(const float* __restrict__ x,
                                              const float* __restrict__ vb,
                                              const int* __restrict__ batch,
                                              const float* __restrict__ colsum,
                                              const float* __restrict__ colsum2,
                                              const float* __restrict__ xsum,
                                              const float* __restrict__ xsum2,
                                              float* __restrict__ pooled) {
    const int b = blockIdx.x;
    const int ch = blockIdx.y;          // 0..5: 4 x-chunks, 2 vb-chunks
    const int t = threadIdx.x;

    // cooperative range find for graph b (batch is sorted)
    __shared__ int s_cnt[4];
    __shared__ int s_st;
    int c = 0;
    for (int n = t; n < N_NODES; n += 256) {
        int bb = batch[n];
        int pb = (n == 0) ? -1 : batch[n - 1];
        c += (bb == b) ? 1 : 0;
        if (bb == b && pb != b) s_st = n;   // at most one thread writes
    }
    #pragma unroll
    for (int off = 32; off > 0; off >>= 1) c += __shfl_down(c, off);
    if ((t & 63) == 0) s_cnt[t >> 6] = c;
    __syncthreads();
    int cnt = s_cnt[0] + s_cnt[1] + s_cnt[2] + s_cnt[3];
    int st = (cnt > 0) ? s_st : 0;
    float ic = (cnt > 0) ? 1.0f / (float)cnt : 0.f;

    float acc = 0.f;
    if (ch < 4) {
        int col = ch * 256 + t;
        float mu  = xsum[col] * (1.0f / N_NODES);
        float var = xsum2[col] * (1.0f / N_NODES) - mu * mu;
        if (var < 0.f) var = 0.f;
        float S = 1.0f / sqrtf(var + EPS);
        const float* base = x + col;
        for (int r = 0; r < cnt; ++r) acc += base[(size_t)(st + r) * F_DIM];
        pooled[b * FH_DIM + col] = (acc * ic - mu) * S;
    } else {
        int col = (ch - 4) * 256 + t;
        float mu  = colsum[col] * (1.0f / N_NODES);
        float var = colsum2[col] * (1.0f / N_NODES) - mu * mu;
        if (var < 0.f) var = 0.f;
        float s1v = 1.0f / sqrtf(var + EPS);
        float v1  = var * s1v * s1v;
        float s2v = 1.0f / sqrtf(v1 + EPS);
        float v2  = v1 * s2v * s2v;
        float s3v = 1.0f / sqrtf(v2 + EPS);
        float S = s1v * s2v * s3v;
        const float* base = vb + col;
        for (int r = 0; r < cnt; ++r) acc += base[(size_t)(st + r) * H_DIM];
        pooled[b * FH_DIM + F_DIM + col] = (acc * ic - mu) * S;
    }
}

// ---------------- K8: h1 = relu(pooled @ fc1_w^T + b1), float4 ----------------
__global__ __launch_bounds__(256) void k_fc1(const float* __restrict__ pooled,
                                             const float* __restrict__ w,
                                             const float* __restrict__ bias,
                                             float* __restrict__ h1) {
    int wid = (blockIdx.x * 256 + threadIdx.x) >> 6;   // 0..8191
    int lane = threadIdx.x & 63;
    int b = wid >> 9, o = wid & 511;
    const float4* pr = (const float4*)(pooled + b * FH_DIM);
    const float4* wr = (const float4*)(w + o * FH_DIM);
    float acc = 0.f;
    #pragma unroll
    for (int k = 0; k < 6; ++k) {                      // 6*64 = 384 = FH_DIM/4
        float4 a = pr[k * 64 + lane];
        float4 v = wr[k * 64 + lane];
        acc += a.x * v.x + a.y * v.y + a.z * v.z + a.w * v.w;
    }
    #pragma unroll
    for (int off = 32; off > 0; off >>= 1) acc += __shfl_down(acc, off);
    if (lane == 0) h1[b * H_DIM + o] = fmaxf(acc + bias[o], 0.f);
}

// ---------------- K9: out = h1 @ fc2_w^T + b2, float4 ----------------
__global__ __launch_bounds__(256) void k_fc2(const float* __restrict__ h1,
                                             const float* __restrict__ w,
                                             const float* __restrict__ bias,
                                             float* __restrict__ outp) {
    int wid = (blockIdx.x * 256 + threadIdx.x) >> 6;
    int lane = threadIdx.x & 63;
    if (wid >= B_GRAPHS * OUT_DIM) return;
    int b = wid / OUT_DIM, u = wid % OUT_DIM;
    const float4* hr = (const float4*)(h1 + b * H_DIM);
    const float4* wr = (const float4*)(w + u * H_DIM);
    float acc = 0.f;
    #pragma unroll
    for (int k = 0; k < 2; ++k) {                      // 2*64 = 128 = H_DIM/4
        float4 a = hr[k * 64 + lane];
        float4 v = wr[k * 64 + lane];
        acc += a.x * v.x + a.y * v.y + a.z * v.z + a.w * v.w;
    }
    #pragma unroll
    for (int off = 32; off > 0; off >>= 1) acc += __shfl_down(acc, off);
    if (lane == 0) outp[b * OUT_DIM + u] = acc + bias[u];
}

extern "C" void kernel_launch(void* const* d_in, const int* in_sizes, int n_in,
                              void* d_out, int out_size, void* d_ws, size_t ws_size,
                              hipStream_t stream) {
    const float* x       = (const float*)d_in[0];
    const float* w_att   = (const float*)d_in[1];
    const float* wk_scale= (const float*)d_in[2];
    const float* wk_trans= (const float*)d_in[3];
    const float* wk_wav  = (const float*)d_in[4];
    const float* wk_base = (const float*)d_in[5];
    const float* fc1_w   = (const float*)d_in[6];
    const float* fc1_b   = (const float*)d_in[7];
    const float* fc2_w   = (const float*)d_in[8];
    const float* fc2_b   = (const float*)d_in[9];
    const int*   eidx    = (const int*)d_in[10];
    const int*   batch   = (const int*)d_in[11];
    float* outp = (float*)d_out;

    float* ws = (float*)d_ws;
    const int NH = N_NODES * H_DIM;            // 524288
    float* h      = ws;                        // 524288
    float* agg    = h + NH;                    // 524288
    float* aggT   = agg + NH;                  // 524288
    float* pk     = aggT + NH;                 // 1048576
    float* vb     = pk + 4 * (H_DIM * H_DIM);  // 524288
    float* colsum = vb + NH;                   // 512
    float* colsum2= colsum + 512;              // 512
    float* xsum   = colsum2 + 512;             // 1024
    float* xsum2  = xsum + 1024;               // 1024
    int*   deg    = (int*)(xsum2 + 1024);      // 1024
    int*   estart = deg + N_NODES;
    int*   cursor = estart + N_NODES;
    int*   elist  = cursor + N_NODES;          // 32768
    float* pooled = (float*)(elist + E_EDGES); // 24576
    float* h1     = pooled + B_GRAPHS * FH_DIM;// 8192

    const int* src = eidx;
    const int* dst = eidx + E_EDGES;

    // 1. fused setup: h + pk + zero(stats,deg) + zero(vb)
    k_setup<<<5136, 256, 0, stream>>>(x, w_att, h, wk_scale, wk_trans, wk_wav,
                                      pk, colsum, vb);
    // 2. fused hist + xstats
    k_hx<<<192, 256, 0, stream>>>(dst, deg, x, xsum, xsum2);
    // 3-4. scan, fill
    k_scan<<<1, N_NODES, 0, stream>>>(deg, estart, cursor);
    k_fill<<<E_EDGES / 256, 256, 0, stream>>>(src, dst, cursor, elist);
    // 5. gather
    k_gather<<<N_NODES, 256, 0, stream>>>(h, estart, deg, elist, agg);
    // 6. transpose
    {
        dim3 grid(N_NODES / 64, H_DIM / 64);
        k_transpose<<<grid, 256, 0, stream>>>(agg, aggT);
    }
    // 7. base GEMM (atomic into vb)
    {
        dim3 grid(N_NODES / 32, H_DIM / 32);
        k_base<<<grid, 256, 0, stream>>>(aggT, wk_base, vb);
    }
    // 8. wavelet (atomic into vb)
    {
        dim3 grid(N_NODES / TN, H_DIM / TO, ZSPLIT);
        k_wavelet<<<grid, 256, 0, stream>>>(aggT, pk, vb);
    }
    // 9. column stats of vb
    k_stats<<<16, 256, 0, stream>>>(vb, colsum, colsum2);
    // 10. pool (inline BN params + graph ranges)
    {
        dim3 grid(B_GRAPHS, 6);
        k_pool<<<grid, 256, 0, stream>>>(x, vb, batch, colsum, colsum2, xsum, xsum2, pooled);
    }
    // 11-12. fc1, fc2
    k_fc1<<<(B_GRAPHS * H_DIM * 64) / 256, 256, 0, stream>>>(pooled, fc1_w, fc1_b, h1);
    k_fc2<<<(B_GRAPHS * OUT_DIM * 64 + 255) / 256, 256, 0, stream>>>(h1, fc2_w, fc2_b, outp);
}